// Round 1
// baseline (25.340 us; speedup 1.0000x reference)
//
#include <hip/hip_runtime.h>

#define LN_EPS 1e-5f

// One block per sample n. 512 threads = one per d column.
// Each thread: load x[n, 0..7, d], stable-descending sort (network),
// Choquet accumulate y[0..7] via FM gather from LDS, block LayerNorm, PReLU.
__global__ __launch_bounds__(512) void choquet_fused_kernel(
    const float* __restrict__ x,      // (N, 8, 512)
    const float* __restrict__ FM,     // (255, 8)
    const float* __restrict__ lnw,    // (8, 512)
    const float* __restrict__ lnb,    // (8, 512)
    const float* __restrict__ prelu,  // (1,)
    float* __restrict__ out)          // (N, 8, 512)
{
    constexpr int S = 8, D = 512, H = 8;
    __shared__ float fm_s[255 * 9];   // rows padded 8 -> 9 floats (bank spread)
    __shared__ float red[16];         // 8 waves x {sum, sumsq}
    __shared__ float stats[2];        // mean, rstd

    const int n = blockIdx.x;
    const int d = threadIdx.x;

    // Stage FM (255x8 = 8160 B) into LDS, padded row stride 9.
    for (int i = threadIdx.x; i < 255 * 8; i += 512) {
        int r = i >> 3, c = i & 7;
        fm_s[r * 9 + c] = FM[i];
    }
    __syncthreads();

    // Load the 8 source values for this column (coalesced per s).
    const float* xp = x + (size_t)n * S * D + d;
    float v0 = xp[0 * D], v1 = xp[1 * D], v2 = xp[2 * D], v3 = xp[3 * D];
    float v4 = xp[4 * D], v5 = xp[5 * D], v6 = xp[6 * D], v7 = xp[7 * D];
    int i0 = 0, i1 = 1, i2 = 2, i3 = 3, i4 = 4, i5 = 5, i6 = 6, i7 = 7;

    // Stable descending sort: total order (val desc, idx asc),
    // 19-comparator optimal 8-element network.
#define CE(a, b)                                                              \
    {                                                                         \
        bool sw = (v##a < v##b) || (v##a == v##b && i##a > i##b);             \
        if (sw) {                                                             \
            float tv = v##a; v##a = v##b; v##b = tv;                          \
            int   ti = i##a; i##a = i##b; i##b = ti;                          \
        }                                                                     \
    }
    CE(0, 1) CE(2, 3) CE(4, 5) CE(6, 7)
    CE(0, 2) CE(1, 3) CE(4, 6) CE(5, 7)
    CE(1, 2) CE(5, 6) CE(0, 4) CE(3, 7)
    CE(1, 5) CE(2, 6)
    CE(1, 4) CE(3, 6)
    CE(2, 4) CE(3, 5)
    CE(3, 4)
#undef CE

    // Choquet accumulation: latt = (running OR of 2^idx) - 1.
    float y[H];
#pragma unroll
    for (int h = 0; h < H; ++h) y[h] = 0.f;

    int mask = 0;
#define STEP(vs, is, vnext)                                                   \
    {                                                                         \
        mask |= (1 << (is));                                                  \
        const float diff = (vs) - (vnext);                                    \
        const float* row = &fm_s[(mask - 1) * 9];                             \
        _Pragma("unroll")                                                     \
        for (int h = 0; h < H; ++h) y[h] += diff * row[h];                    \
    }
    STEP(v0, i0, v1)
    STEP(v1, i1, v2)
    STEP(v2, i2, v3)
    STEP(v3, i3, v4)
    STEP(v4, i4, v5)
    STEP(v5, i5, v6)
    STEP(v6, i6, v7)
    STEP(v7, i7, 0.0f)
#undef STEP

    // Block reduction for mean/var over all H*D = 4096 values.
    float s1 = 0.f, s2 = 0.f;
#pragma unroll
    for (int h = 0; h < H; ++h) { s1 += y[h]; s2 += y[h] * y[h]; }
#pragma unroll
    for (int off = 32; off > 0; off >>= 1) {
        s1 += __shfl_down(s1, off);
        s2 += __shfl_down(s2, off);
    }
    const int wid = threadIdx.x >> 6;
    const int lane = threadIdx.x & 63;
    if (lane == 0) { red[wid * 2] = s1; red[wid * 2 + 1] = s2; }
    __syncthreads();
    if (threadIdx.x == 0) {
        float t1 = 0.f, t2 = 0.f;
#pragma unroll
        for (int w = 0; w < 8; ++w) { t1 += red[w * 2]; t2 += red[w * 2 + 1]; }
        const float mean = t1 * (1.0f / 4096.0f);
        float var = t2 * (1.0f / 4096.0f) - mean * mean;
        var = var < 0.f ? 0.f : var;
        stats[0] = mean;
        stats[1] = rsqrtf(var + LN_EPS);
    }
    __syncthreads();

    const float mean = stats[0];
    const float rstd = stats[1];
    const float pw = prelu[0];
    float* op = out + (size_t)n * H * D + d;
#pragma unroll
    for (int h = 0; h < H; ++h) {
        float val = (y[h] - mean) * rstd * lnw[h * D + d] + lnb[h * D + d];
        op[h * D] = val > 0.f ? val : pw * val;
    }
}

extern "C" void kernel_launch(void* const* d_in, const int* in_sizes, int n_in,
                              void* d_out, int out_size, void* d_ws, size_t ws_size,
                              hipStream_t stream) {
    const float* x     = (const float*)d_in[0];
    const float* FM    = (const float*)d_in[1];
    const float* lnw   = (const float*)d_in[2];
    const float* lnb   = (const float*)d_in[3];
    const float* prelu = (const float*)d_in[4];
    float* out = (float*)d_out;

    const int N = 2048;
    choquet_fused_kernel<<<N, 512, 0, stream>>>(x, FM, lnw, lnb, prelu, out);
}

// Round 2
// 24.554 us; speedup vs baseline: 1.0320x; 1.0320x over previous
//
#include <hip/hip_runtime.h>

#define LN_EPS 1e-5f

// One block per sample n. 512 threads = one per d column.
__global__ __launch_bounds__(512) void choquet_fused_kernel(
    const float* __restrict__ x,      // (N, 8, 512)
    const float* __restrict__ FM,     // (255, 8)
    const float* __restrict__ lnw,    // (8, 512)
    const float* __restrict__ lnb,    // (8, 512)
    const float* __restrict__ prelu,  // (1,)
    float* __restrict__ out)          // (N, 8, 512)
{
    constexpr int S = 8, D = 512, H = 8;
    // FM rows padded 8 -> 10 dwords (40 B): 8B-aligned rows for b64 reads,
    // start bank 10r mod 32 spreads over 16 banks.
    __shared__ float2 fm_s[255 * 5];
    __shared__ float red[16];         // 8 waves x {sum, sumsq}

    const int n = blockIdx.x;
    const int d = threadIdx.x;

    // ---- issue all global loads up front so latency hides under compute ----
    const float* xp = x + (size_t)n * S * D + d;
    float v0 = xp[0 * D], v1 = xp[1 * D], v2 = xp[2 * D], v3 = xp[3 * D];
    float v4 = xp[4 * D], v5 = xp[5 * D], v6 = xp[6 * D], v7 = xp[7 * D];

    // prefetch LayerNorm params (L2/L3-hot after first blocks)
    float w[H], b[H];
#pragma unroll
    for (int h = 0; h < H; ++h) { w[h] = lnw[h * D + d]; b[h] = lnb[h * D + d]; }
    const float pw = prelu[0];

    // stage FM: 255*8 dwords = 510 float4 loads, scattered to stride-10 rows
    if (threadIdx.x < 510) {
        const float4 v = ((const float4*)FM)[threadIdx.x];
        const int r = threadIdx.x >> 1, half = threadIdx.x & 1;
        fm_s[5 * r + 2 * half]     = make_float2(v.x, v.y);
        fm_s[5 * r + 2 * half + 1] = make_float2(v.z, v.w);
    }

    int i0 = 0, i1 = 1, i2 = 2, i3 = 3, i4 = 4, i5 = 5, i6 = 6, i7 = 7;

    // Stable descending sort: total order (val desc, idx asc), 19 comparators.
#define CE(a, b)                                                              \
    {                                                                         \
        bool sw = (v##a < v##b) || (v##a == v##b && i##a > i##b);             \
        if (sw) {                                                             \
            float tv = v##a; v##a = v##b; v##b = tv;                          \
            int   ti = i##a; i##a = i##b; i##b = ti;                          \
        }                                                                     \
    }
    CE(0, 1) CE(2, 3) CE(4, 5) CE(6, 7)
    CE(0, 2) CE(1, 3) CE(4, 6) CE(5, 7)
    CE(1, 2) CE(5, 6) CE(0, 4) CE(3, 7)
    CE(1, 5) CE(2, 6)
    CE(1, 4) CE(3, 6)
    CE(2, 4) CE(3, 5)
    CE(3, 4)
#undef CE

    __syncthreads();   // FM staged

    // Choquet accumulation: latt = (running OR of 2^idx) - 1.
    float y[H];
#pragma unroll
    for (int h = 0; h < H; ++h) y[h] = 0.f;

    int mask = 0;
#define STEP(vs, is, vnext)                                                   \
    {                                                                         \
        mask |= (1 << (is));                                                  \
        const float diff = (vs) - (vnext);                                    \
        const float2* row = &fm_s[5 * (mask - 1)];                            \
        const float2 r0 = row[0], r1 = row[1], r2 = row[2], r3 = row[3];      \
        y[0] += diff * r0.x; y[1] += diff * r0.y;                             \
        y[2] += diff * r1.x; y[3] += diff * r1.y;                             \
        y[4] += diff * r2.x; y[5] += diff * r2.y;                             \
        y[6] += diff * r3.x; y[7] += diff * r3.y;                             \
    }
    STEP(v0, i0, v1)
    STEP(v1, i1, v2)
    STEP(v2, i2, v3)
    STEP(v3, i3, v4)
    STEP(v4, i4, v5)
    STEP(v5, i5, v6)
    STEP(v6, i6, v7)
    STEP(v7, i7, 0.0f)
#undef STEP

    // Block mean/var over H*D = 4096 values: wave butterfly, then all
    // threads combine the 8 wave-partials (no second barrier / serial lane0).
    float s1 = 0.f, s2 = 0.f;
#pragma unroll
    for (int h = 0; h < H; ++h) { s1 += y[h]; s2 += y[h] * y[h]; }
#pragma unroll
    for (int off = 32; off > 0; off >>= 1) {
        s1 += __shfl_xor(s1, off);
        s2 += __shfl_xor(s2, off);
    }
    const int wid = threadIdx.x >> 6;
    if ((threadIdx.x & 63) == 0) { red[wid * 2] = s1; red[wid * 2 + 1] = s2; }
    __syncthreads();

    float t1 = 0.f, t2 = 0.f;
#pragma unroll
    for (int wv = 0; wv < 8; ++wv) { t1 += red[wv * 2]; t2 += red[wv * 2 + 1]; }
    const float mean = t1 * (1.0f / 4096.0f);
    float var = t2 * (1.0f / 4096.0f) - mean * mean;
    var = var < 0.f ? 0.f : var;
    const float rstd = rsqrtf(var + LN_EPS);

    float* op = out + (size_t)n * H * D + d;
#pragma unroll
    for (int h = 0; h < H; ++h) {
        float val = (y[h] - mean) * rstd * w[h] + b[h];
        op[h * D] = val > 0.f ? val : pw * val;
    }
}

extern "C" void kernel_launch(void* const* d_in, const int* in_sizes, int n_in,
                              void* d_out, int out_size, void* d_ws, size_t ws_size,
                              hipStream_t stream) {
    const float* x     = (const float*)d_in[0];
    const float* FM    = (const float*)d_in[1];
    const float* lnw   = (const float*)d_in[2];
    const float* lnb   = (const float*)d_in[3];
    const float* prelu = (const float*)d_in[4];
    float* out = (float*)d_out;

    const int N = in_sizes[0] / (8 * 512);
    choquet_fused_kernel<<<N, 512, 0, stream>>>(x, FM, lnw, lnb, prelu, out);
}